// Round 24
// baseline (159.171 us; speedup 1.0000x reference)
//
#include <hip/hip_runtime.h>
#include <math.h>

#define BN_ 16
#define SS  2048
#define HH  1024

typedef unsigned short u16;
typedef unsigned int   u32;
typedef __bf16 bf16x8 __attribute__((ext_vector_type(8)));
typedef float  f32x4  __attribute__((ext_vector_type(4)));
typedef float  f32x16 __attribute__((ext_vector_type(16)));
#define MFMA16 __builtin_amdgcn_mfma_f32_16x16x32_bf16
#define MFMA32 __builtin_amdgcn_mfma_f32_32x32x16_bf16

// ---------------- ws layout (float offsets) ----------------
#define QK_OFF    0
#define QK_FLOATS (BN_*SS*64)           // bf16 qk[32768][128]
#define WT_OFF    (QK_OFF + QK_FLOATS)  // bf16 wt[128][1024]
#define WT_FLOATS (64*HH)
#define CP_OFF    (WT_OFF + WT_FLOATS)  // cpart[16][32][2][2048]
#define CP_FLOATS (BN_*32*2*SS)
#define NB_OFF    (CP_OFF + CP_FLOATS)  // nbv [16]
#define NBW_OFF   (NB_OFF + 16)         // nbw [16]
#define U_OFF     (NBW_OFF + 16)        // u[16][1024] fp32 (atomic-accumulated)
#define XB_OFF    (U_OFF + BN_*HH)      // optional bf16 x copy [32768][1024]

__device__ __forceinline__ u16 f2b(float f) {
    unsigned u = __builtin_bit_cast(unsigned, f);
    return (u16)((u + 0x7FFFu + ((u >> 16) & 1u)) >> 16);
}

__device__ __forceinline__ bf16x8 cvt8(float4 a, float4 b) {
    bf16x8 r;
    r[0] = (__bf16)a.x; r[1] = (__bf16)a.y; r[2] = (__bf16)a.z; r[3] = (__bf16)a.w;
    r[4] = (__bf16)b.x; r[5] = (__bf16)b.y; r[6] = (__bf16)b.z; r[7] = (__bf16)b.w;
    return r;
}

// swizzled elem index in a [rows][64] bf16 LDS tile (row stride 128B)
__device__ __forceinline__ int swze(int row, int e) {
    return row * 64 + (e ^ ((row & 7) << 3));
}

// MFMA16 A/B fragment from swizzled tile
__device__ __forceinline__ bf16x8 ldfrag(const u16* t, int row16, int ks, int l6) {
    int row = row16 + (l6 & 15);
    int e = ks * 32 + ((l6 >> 4) << 3);
    return *(const bf16x8*)&t[swze(row, e)];
}

// async global->LDS, 16B per lane; LDS dest = wave-uniform base + lane*16
__device__ __forceinline__ void gload16(const u16* g, u16* l) {
    __builtin_amdgcn_global_load_lds(
        (const __attribute__((address_space(1))) u32*)g,
        (__attribute__((address_space(3))) u32*)l, 16, 0, 0);
}

// ---- prep: coalesced wt transpose (0..63) + Nb (64..79) + zero u/out0 (80..95) ----
__global__ __launch_bounds__(256) void k_prep(const float* __restrict__ Wq,
                                              const float* __restrict__ Wk,
                                              const int* __restrict__ mask,
                                              u16* __restrict__ wt,
                                              float* __restrict__ nbv,
                                              float* __restrict__ nbw,
                                              float* __restrict__ u,
                                              float* __restrict__ outz) {
    int bid = blockIdx.x, tid = threadIdx.x;
    if (bid < 64) {
        int i4 = tid >> 6, n = tid & 63;          // coalesced reads: n contiguous
        #pragma unroll
        for (int ii = 0; ii < 4; ++ii) {
            int k = bid * 16 + ii * 4 + i4;
            wt[(size_t)n * HH + k]        = f2b(Wq[(size_t)k * 64 + n]);
            wt[(size_t)(64 + n) * HH + k] = f2b(Wk[(size_t)k * 64 + n]);
        }
    } else if (bid < 80) {
        int b = bid - 64;
        int s = 0;
        for (int i = tid; i < SS; i += 256) s += mask[b * SS + i];
        float fs = (float)s;
        for (int off = 1; off < 64; off <<= 1) fs += __shfl_xor(fs, off);
        __shared__ float red[4];
        if ((tid & 63) == 0) red[tid >> 6] = fs;
        __syncthreads();
        if (tid == 0) {
            float t = red[0] + red[1] + red[2] + red[3];
            nbv[b] = t + 1e-8f;
            nbw[b] = t / (t + 1e-8f);
        }
    } else {
        int zb = bid - 80;                        // 0..15, 2048 floats each
        float* dst = (zb < 8) ? (u + zb * 2048) : (outz + (zb - 8) * 2048);
        for (int i = tid; i < 2048; i += 256) dst[i] = 0.f;
    }
}

// ---- QK projection: 4-buf gload_lds, 2 K-tiles per barrier (r22 best); ----
// ---- optionally persists bf16 x copy (WX=1) for k_u. ----
template<int WX>
__global__ __launch_bounds__(256) void k_qkproj(const float* __restrict__ x,
                                                const u16* __restrict__ wt,
                                                const float* __restrict__ bq,
                                                const float* __restrict__ bk,
                                                u16* __restrict__ qk,
                                                u16* __restrict__ xb16) {
    __shared__ __align__(16) u16 Bs[4][128 * 64];
    int tid = threadIdx.x, l6 = tid & 63, w = tid >> 6;
    int lr = l6 & 15, lk = l6 >> 4;
    int row = blockIdx.x * 64 + w * 16;
    const float* xr = x + (size_t)(row + lr) * HH + lk * 8;
    int r0 = tid >> 3, j = tid & 7;
    const u16* bsrc = wt + (size_t)r0 * HH + (j ^ (r0 & 7)) * 8;
    float4 xa0[4], xa1[4];
    #define GLOADB(kt, BI) { const u16* s_ = bsrc + (kt) * 64; u16* l_ = Bs[BI] + tid * 8;  \
        gload16(s_,            l_);        gload16(s_ + 32 * HH, l_ + 2048);                \
        gload16(s_ + 64 * HH,  l_ + 4096); gload16(s_ + 96 * HH, l_ + 6144); }
    #define LOADA(kt, A_) { const float* p_ = xr + (kt) * 64;                               \
        A_[0] = *(const float4*)p_;        A_[1] = *(const float4*)(p_ + 4);                \
        A_[2] = *(const float4*)(p_ + 32); A_[3] = *(const float4*)(p_ + 36); }
    #define COMP(BI, A_, kt) { const u16* Bp = Bs[BI];                                      \
        bf16x8 a0 = cvt8(A_[0], A_[1]);                                                     \
        bf16x8 a1 = cvt8(A_[2], A_[3]);                                                     \
        if (WX) {                                                                           \
            u16* xp_ = xb16 + (size_t)(row + lr) * HH + (kt) * 64 + lk * 8;                 \
            *(bf16x8*)xp_ = a0;                                                             \
            *(bf16x8*)(xp_ + 32) = a1;                                                      \
        }                                                                                   \
        _Pragma("unroll")                                                                   \
        for (int jj = 0; jj < 8; ++jj) {                                                    \
            bf16x8 b0 = ldfrag(Bp, jj * 16, 0, l6);                                         \
            bf16x8 b1 = ldfrag(Bp, jj * 16, 1, l6);                                         \
            acc[jj] = MFMA16(a0, b0, acc[jj], 0, 0, 0);                                     \
            acc[jj] = MFMA16(a1, b1, acc[jj], 0, 0, 0);                                     \
        } }

    f32x4 acc[8];
    #pragma unroll
    for (int jj = 0; jj < 8; ++jj) acc[jj] = (f32x4){0.f, 0.f, 0.f, 0.f};

    GLOADB(0, 0); GLOADB(1, 1); LOADA(0, xa0); LOADA(1, xa1);
    __syncthreads();
    for (int p = 0; p < 8; ++p) {
        int k0 = 2 * p;
        if (p < 7) { GLOADB(k0 + 2, (k0 + 2) & 3); GLOADB(k0 + 3, (k0 + 3) & 3); }
        __builtin_amdgcn_s_setprio(1);
        COMP(k0 & 3, xa0, k0);
        __builtin_amdgcn_s_setprio(0);
        if (p < 7) LOADA(k0 + 2, xa0);
        __builtin_amdgcn_s_setprio(1);
        COMP((k0 + 1) & 3, xa1, k0 + 1);
        __builtin_amdgcn_s_setprio(0);
        if (p < 7) {
            LOADA(k0 + 3, xa1);
            __syncthreads();
        }
    }
    #pragma unroll
    for (int jj = 0; jj < 8; ++jj) {
        int n = jj * 16 + lr;
        float bias = (n < 64) ? bq[n] : bk[n - 64];
        int mrow = row + lk * 4;
        #pragma unroll
        for (int r4 = 0; r4 < 4; ++r4)
            qk[(size_t)(mrow + r4) * 128 + n] = f2b(acc[jj][r4] + bias);
    }
    #undef GLOADB
    #undef LOADA
    #undef COMP
}

// ---- score: 32x32 MFMA, wave owns 32 cols; 4-buf gload_lds, 2 tiles/barrier ----
// acc layout (m74/m101): col = lane&31, row = (reg&3) + 8*(reg>>2) + 4*(lane>>5)
__global__ __launch_bounds__(256) void k_score(const u16* __restrict__ qk,
                                               const int* __restrict__ mask,
                                               float* __restrict__ cpart) {
    __shared__ __align__(16) u16 Ks[4 * 8192];
    __shared__ float pml[SS];          // additive key mask: 0 or -1e30
    __shared__ float redbuf[4][64];
    __shared__ float lshs[64];
    // XCD-locality remap (T1): each XCD owns 2 whole batches -> K-half L2-resident
    int l = blockIdx.x;
    int b = (l & 7) * 2 + ((l >> 3) >> 5);
    int sb = (l >> 3) & 31;
    int tid = threadIdx.x, l6 = tid & 63, w = tid >> 6;
    int cl = l6 & 31, hi = l6 >> 5;
    for (int i = tid; i < SS; i += 256) pml[i] = mask[b * SS + i] ? 0.f : -1e30f;
    const u16* qkb = qk + (size_t)b * SS * 128;
    int q0 = sb * 64;
    bf16x8 qA[2][4];
    #pragma unroll
    for (int rs = 0; rs < 2; ++rs)
        #pragma unroll
        for (int ks = 0; ks < 4; ++ks)
            qA[rs][ks] = *(const bf16x8*)&qkb[(size_t)(q0 + rs * 32 + cl) * 128 + ks * 16 + hi * 8];
    int r0 = tid >> 3, j = tid & 7;
    const u16* ksrc = qkb + 64 + (size_t)r0 * 128 + (j ^ (r0 & 7)) * 8;
    #define GLOADK(tt, BI) { const u16* s_ = ksrc + (size_t)(tt) * (128 * 128);             \
        u16* l_ = Ks + (BI) * 8192 + tid * 8;                                               \
        gload16(s_,             l_);        gload16(s_ + 32 * 128, l_ + 2048);              \
        gload16(s_ + 64 * 128,  l_ + 4096); gload16(s_ + 96 * 128, l_ + 6144); }

    const float SCL = 0.18033688f;     // log2(e)/8
    float rsum[2][16];
    #pragma unroll
    for (int rs = 0; rs < 2; ++rs)
        #pragma unroll
        for (int r = 0; r < 16; ++r) rsum[rs][r] = 0.f;

    #define P1C(tt, BI) { const u16* KsB = Ks + (BI) * 8192;                                \
        bf16x8 kB[4];                                                                       \
        _Pragma("unroll")                                                                   \
        for (int ks = 0; ks < 4; ++ks)                                                      \
            kB[ks] = *(const bf16x8*)&KsB[swze(w * 32 + cl, ks * 16 + hi * 8)];             \
        float pmv = pml[(tt) * 128 + w * 32 + cl];                                          \
        __builtin_amdgcn_s_setprio(1);                                                      \
        _Pragma("unroll")                                                                   \
        for (int rs = 0; rs < 2; ++rs) {                                                    \
            f32x16 a_ = {};                                                                 \
            _Pragma("unroll")                                                               \
            for (int ks = 0; ks < 4; ++ks) a_ = MFMA32(qA[rs][ks], kB[ks], a_, 0, 0, 0);    \
            _Pragma("unroll")                                                               \
            for (int r = 0; r < 16; ++r)                                                    \
                rsum[rs][r] += exp2f(fmaf(a_[r], SCL, pmv));                                \
        }                                                                                   \
        __builtin_amdgcn_s_setprio(0); }

    GLOADK(0, 0); GLOADK(1, 1);
    __syncthreads();                   // pml + tiles 0,1 resident
    for (int p = 0; p < 8; ++p) {
        int t0 = 2 * p;
        if (p < 7) { GLOADK(t0 + 2, (t0 + 2) & 3); GLOADK(t0 + 3, (t0 + 3) & 3); }
        P1C(t0, t0 & 3);
        P1C(t0 + 1, (t0 + 1) & 3);
        if (p < 7) __syncthreads();
    }
    // reduce over this wave's 32 cols (low 5 lane bits)
    #pragma unroll
    for (int off = 1; off < 32; off <<= 1)
        #pragma unroll
        for (int rs = 0; rs < 2; ++rs)
            #pragma unroll
            for (int r = 0; r < 16; ++r)
                rsum[rs][r] += __shfl_xor(rsum[rs][r], off);
    if (cl == 0) {
        #pragma unroll
        for (int rs = 0; rs < 2; ++rs)
            #pragma unroll
            for (int r = 0; r < 16; ++r)
                redbuf[w][rs * 32 + (r & 3) + 8 * (r >> 2) + 4 * hi] = rsum[rs][r];
    }
    GLOADK(0, 0); GLOADK(1, 1);        // prefetch pass-2 tiles (bufs 0,1 free since p=6)
    __syncthreads();
    if (tid < 64) {
        float lv = redbuf[0][tid] + redbuf[1][tid] + redbuf[2][tid] + redbuf[3][tid];
        lshs[tid] = (lv > 0.f) ? -log2f(lv) : -1e30f;
    }
    __syncthreads();
    float lsh[2][16];
    unsigned qmb = 0;
    #pragma unroll
    for (int rs = 0; rs < 2; ++rs)
        #pragma unroll
        for (int r = 0; r < 16; ++r) {
            int rowi = rs * 32 + (r & 3) + 8 * (r >> 2) + 4 * hi;
            lsh[rs][r] = lshs[rowi];
            qmb |= (pml[q0 + rowi] == 0.f ? 1u : 0u) << (rs * 16 + r);
        }

    #define P2C(tt, BI) { const u16* KsB = Ks + (BI) * 8192;                                \
        bf16x8 kB[4];                                                                       \
        _Pragma("unroll")                                                                   \
        for (int ks = 0; ks < 4; ++ks)                                                      \
            kB[ks] = *(const bf16x8*)&KsB[swze(w * 32 + cl, ks * 16 + hi * 8)];             \
        float pmv = pml[(tt) * 128 + w * 32 + cl];                                          \
        float sa = 0.f, sm = 0.f;                                                           \
        __builtin_amdgcn_s_setprio(1);                                                      \
        _Pragma("unroll")                                                                   \
        for (int rs = 0; rs < 2; ++rs) {                                                    \
            f32x16 a_ = {};                                                                 \
            _Pragma("unroll")                                                               \
            for (int ks = 0; ks < 4; ++ks) a_ = MFMA32(qA[rs][ks], kB[ks], a_, 0, 0, 0);    \
            _Pragma("unroll")                                                               \
            for (int r = 0; r < 16; ++r) {                                                  \
                float e_ = exp2f(fmaf(a_[r], SCL, lsh[rs][r]) + pmv);                       \
                sa += e_;                                                                   \
                sm += ((qmb >> (rs * 16 + r)) & 1u) ? e_ : 0.f;                             \
            }                                                                               \
        }                                                                                   \
        __builtin_amdgcn_s_setprio(0);                                                      \
        sa += __shfl_xor(sa, 32); sm += __shfl_xor(sm, 32);                                 \
        if (hi == 0) {                                                                      \
            size_t b_ = (((size_t)b * 32 + sb) * 2) * SS + (size_t)(tt) * 128 + w * 32 + cl; \
            cpart[b_] = sa; cpart[b_ + SS] = sm;                                            \
        } }

    for (int p = 0; p < 8; ++p) {
        int t0 = 2 * p;
        if (p < 7) { GLOADK(t0 + 2, (t0 + 2) & 3); GLOADK(t0 + 3, (t0 + 3) & 3); }
        P2C(t0, t0 & 3);
        P2C(t0 + 1, (t0 + 1) & 3);
        if (p < 7) __syncthreads();
    }
    #undef GLOADK
    #undef P1C
    #undef P2C
}

// ---- shared finalize (w + attn_mean from cpart) helper via macro body ----
#define KU_HEAD()                                                                   \
    __shared__ float wl[64];                                                        \
    __shared__ float red2[2][4][64];                                                \
    int b = blockIdx.x, ch = blockIdx.y;                                            \
    int tid = threadIdx.x, tl = tid & 63, qd = tid >> 6;                            \
    int t = ch * 64 + tl;                                                           \
    {                                                                               \
        float sa = 0.f, sm = 0.f;                                                   \
        _Pragma("unroll")                                                           \
        for (int k = 0; k < 8; ++k) {                                               \
            const float* p = &cpart[(((size_t)b * 32 + (qd * 8 + k)) * 2) * SS + t];\
            sa += p[0];                                                             \
            sm += p[SS];                                                            \
        }                                                                           \
        red2[0][qd][tl] = sa;                                                       \
        red2[1][qd][tl] = sm;                                                       \
    }                                                                               \
    __syncthreads();                                                                \
    if (tid < 64) {                                                                 \
        float sat = red2[0][0][tl] + red2[0][1][tl] + red2[0][2][tl] + red2[0][3][tl]; \
        float smt = red2[1][0][tl] + red2[1][1][tl] + red2[1][2][tl] + red2[1][3][tl]; \
        float pm = mask[b * SS + t] ? 1.f : 0.f;                                    \
        out_mean[b * SS + t] = sat * pm * (1.f / SS);                               \
        wl[tl] = smt * pm / nbv[b];                                                 \
    }                                                                               \
    __syncthreads();

// ---- k_u (fp32-x fallback) ----
__global__ __launch_bounds__(256) void k_u(const float* __restrict__ x,
                                           const float* __restrict__ cpart,
                                           const int* __restrict__ mask,
                                           const float* __restrict__ nbv,
                                           float* __restrict__ u,
                                           float* __restrict__ out_mean) {
    KU_HEAD();
    const float* xb = &x[((size_t)b * SS + ch * 64) * HH + tid * 4];
    float4 acc = {0.f, 0.f, 0.f, 0.f};
    #pragma unroll 16
    for (int tt = 0; tt < 64; ++tt) {
        float4 xv = *(const float4*)&xb[(size_t)tt * HH];
        float wv = wl[tt];
        acc.x += wv * xv.x; acc.y += wv * xv.y;
        acc.z += wv * xv.z; acc.w += wv * xv.w;
    }
    float* up = &u[(size_t)b * HH + tid * 4];
    atomicAdd(&up[0], acc.x);
    atomicAdd(&up[1], acc.y);
    atomicAdd(&up[2], acc.z);
    atomicAdd(&up[3], acc.w);
}

// ---- k_u_b (bf16-x): half the HBM traffic ----
__global__ __launch_bounds__(256) void k_u_b(const u16* __restrict__ xb16,
                                             const float* __restrict__ cpart,
                                             const int* __restrict__ mask,
                                             const float* __restrict__ nbv,
                                             float* __restrict__ u,
                                             float* __restrict__ out_mean) {
    KU_HEAD();
    int c8 = (tid & 127) * 8, rh = tid >> 7;       // thread: 8 cols, every 2nd row
    const u16* xb = &xb16[((size_t)b * SS + ch * 64 + rh) * HH + c8];
    float acc[8];
    #pragma unroll
    for (int k = 0; k < 8; ++k) acc[k] = 0.f;
    #pragma unroll 8
    for (int tt = 0; tt < 32; ++tt) {
        bf16x8 xv = *(const bf16x8*)&xb[(size_t)tt * 2 * HH];
        float wv = wl[tt * 2 + rh];
        #pragma unroll
        for (int k = 0; k < 8; ++k) acc[k] = fmaf(wv, (float)xv[k], acc[k]);
    }
    float* up = &u[(size_t)b * HH + c8];
    #pragma unroll
    for (int k = 0; k < 8; ++k) atomicAdd(&up[k], acc[k]);
}

// ---- out0: 256 blocks (16 cb x 16 hb), 64c x 64h Wv tile, 16 acc/thread ----
__global__ __launch_bounds__(256) void k_out0a(const float* __restrict__ u,
                                               const float* __restrict__ Wv,
                                               const float* __restrict__ bv,
                                               const float* __restrict__ nbw,
                                               float* __restrict__ out) {
    __shared__ float uT[64][16];
    __shared__ float red[4][64][16];
    int cb = blockIdx.x, hb = blockIdx.y;
    int c0 = cb * 64, h0 = hb * 64;
    int tid = threadIdx.x;
    int hl = tid & 63, cq = tid >> 6;
    #pragma unroll
    for (int it = 0; it < 4; ++it) {
        int b = it * 4 + cq;
        uT[hl][b] = u[(size_t)b * HH + c0 + hl];
    }
    __syncthreads();
    int h = h0 + hl;
    float acc[16];
    #pragma unroll
    for (int b = 0; b < 16; ++b) acc[b] = 0.f;
    #pragma unroll
    for (int cc = 0; cc < 16; ++cc) {
        int c = cq * 16 + cc;
        float wv = Wv[(size_t)(c0 + c) * HH + h];
        #pragma unroll
        for (int b = 0; b < 16; ++b) acc[b] += uT[c][b] * wv;
    }
    #pragma unroll
    for (int b = 0; b < 16; ++b) red[cq][hl][b] = acc[b];
    __syncthreads();
    #pragma unroll
    for (int it = 0; it < 4; ++it) {
        int b = it * 4 + cq;
        float s = red[0][hl][b] + red[1][hl][b] + red[2][hl][b] + red[3][hl][b];
        if (cb == 0) s += bv[h] * nbw[b];
        atomicAdd(&out[(size_t)b * HH + h], s);
    }
}

extern "C" void kernel_launch(void* const* d_in, const int* in_sizes, int n_in,
                              void* d_out, int out_size, void* d_ws, size_t ws_size,
                              hipStream_t stream) {
    const float* x  = (const float*)d_in[0];
    const int* mask = (const int*)d_in[1];
    const float* Wq = (const float*)d_in[2];
    const float* bq = (const float*)d_in[3];
    const float* Wk = (const float*)d_in[4];
    const float* bk = (const float*)d_in[5];
    const float* Wv = (const float*)d_in[6];
    const float* bv = (const float*)d_in[7];
    float* out = (float*)d_out;
    float* ws  = (float*)d_ws;

    u16*   qk    = (u16*)(ws + QK_OFF);
    u16*   wt    = (u16*)(ws + WT_OFF);
    float* cpart = ws + CP_OFF;
    float* nbv   = ws + NB_OFF;
    float* nbw   = ws + NBW_OFF;
    float* u     = ws + U_OFF;
    u16*   xb16  = (u16*)(ws + XB_OFF);

    // bf16-x path needs XB_OFF floats + 32768*1024 bf16 (deterministic: ws_size fixed)
    size_t need = (size_t)XB_OFF * 4 + (size_t)BN_ * SS * HH * 2;
    bool usexb = ws_size >= need;

    k_prep   <<<dim3(96),         dim3(256), 0, stream>>>(Wq, Wk, mask, wt, nbv, nbw, u, out);
    if (usexb)
        k_qkproj<1> <<<dim3(512), dim3(256), 0, stream>>>(x, wt, bq, bk, qk, xb16);
    else
        k_qkproj<0> <<<dim3(512), dim3(256), 0, stream>>>(x, wt, bq, bk, qk, xb16);
    k_score  <<<dim3(512),        dim3(256), 0, stream>>>(qk, mask, cpart);
    if (usexb)
        k_u_b <<<dim3(BN_, 32),   dim3(256), 0, stream>>>(xb16, cpart, mask, nbv, u, out + BN_ * HH);
    else
        k_u   <<<dim3(BN_, 32),   dim3(256), 0, stream>>>(x, cpart, mask, nbv, u, out + BN_ * HH);
    k_out0a  <<<dim3(16, 16),     dim3(256), 0, stream>>>(u, Wv, bv, nbw, out);
}

// Round 25
// 127.698 us; speedup vs baseline: 1.2465x; 1.2465x over previous
//
#include <hip/hip_runtime.h>
#include <math.h>

#define BN_ 16
#define SS  2048
#define HH  1024

typedef unsigned short u16;
typedef unsigned int   u32;
typedef __bf16 bf16x8 __attribute__((ext_vector_type(8)));
typedef float  f32x4  __attribute__((ext_vector_type(4)));
typedef float  f32x16 __attribute__((ext_vector_type(16)));
#define MFMA16 __builtin_amdgcn_mfma_f32_16x16x32_bf16
#define MFMA32 __builtin_amdgcn_mfma_f32_32x32x16_bf16

// ---------------- ws layout (float offsets) ----------------
#define QK_OFF    0
#define QK_FLOATS (BN_*SS*64)           // bf16 qk[32768][128]
#define WT_OFF    (QK_OFF + QK_FLOATS)  // bf16 wt[128][1024]
#define WT_FLOATS (64*HH)
#define CP_OFF    (WT_OFF + WT_FLOATS)  // cpart[16][32][2][2048]
#define CP_FLOATS (BN_*32*2*SS)
#define NB_OFF    (CP_OFF + CP_FLOATS)  // nbv [16]
#define NBW_OFF   (NB_OFF + 16)         // nbw [16]
#define U_OFF     (NBW_OFF + 16)        // u[16][1024] fp32 (atomic-accumulated)

__device__ __forceinline__ u16 f2b(float f) {
    unsigned u = __builtin_bit_cast(unsigned, f);
    return (u16)((u + 0x7FFFu + ((u >> 16) & 1u)) >> 16);
}

__device__ __forceinline__ bf16x8 cvt8(float4 a, float4 b) {
    bf16x8 r;
    r[0] = (__bf16)a.x; r[1] = (__bf16)a.y; r[2] = (__bf16)a.z; r[3] = (__bf16)a.w;
    r[4] = (__bf16)b.x; r[5] = (__bf16)b.y; r[6] = (__bf16)b.z; r[7] = (__bf16)b.w;
    return r;
}

// swizzled elem index in a [rows][64] bf16 LDS tile (row stride 128B)
__device__ __forceinline__ int swze(int row, int e) {
    return row * 64 + (e ^ ((row & 7) << 3));
}

// MFMA16 A/B fragment from swizzled tile
__device__ __forceinline__ bf16x8 ldfrag(const u16* t, int row16, int ks, int l6) {
    int row = row16 + (l6 & 15);
    int e = ks * 32 + ((l6 >> 4) << 3);
    return *(const bf16x8*)&t[swze(row, e)];
}

// async global->LDS, 16B per lane; LDS dest = wave-uniform base + lane*16
__device__ __forceinline__ void gload16(const u16* g, u16* l) {
    __builtin_amdgcn_global_load_lds(
        (const __attribute__((address_space(1))) u32*)g,
        (__attribute__((address_space(3))) u32*)l, 16, 0, 0);
}

// ---- prep: wt transpose (0..127) + Nb (128..143) + zero u/out0 (144..159) ----
__global__ __launch_bounds__(256) void k_prep(const float* __restrict__ Wq,
                                              const float* __restrict__ Wk,
                                              const int* __restrict__ mask,
                                              u16* __restrict__ wt,
                                              float* __restrict__ nbv,
                                              float* __restrict__ nbw,
                                              float* __restrict__ u,
                                              float* __restrict__ outz) {
    int bid = blockIdx.x, tid = threadIdx.x;
    if (bid < 128) {
        const float* src = (bid < 64) ? &Wq[bid] : &Wk[bid - 64];
        for (int k = tid; k < HH; k += 256)
            wt[(size_t)bid * HH + k] = f2b(src[(size_t)k * 64]);
    } else if (bid < 144) {
        int b = bid - 128;
        int s = 0;
        for (int i = tid; i < SS; i += 256) s += mask[b * SS + i];
        float fs = (float)s;
        for (int off = 1; off < 64; off <<= 1) fs += __shfl_xor(fs, off);
        __shared__ float red[4];
        if ((tid & 63) == 0) red[tid >> 6] = fs;
        __syncthreads();
        if (tid == 0) {
            float t = red[0] + red[1] + red[2] + red[3];
            nbv[b] = t + 1e-8f;
            nbw[b] = t / (t + 1e-8f);
        }
    } else {
        int zb = bid - 144;                           // 0..15, 2048 floats each
        float* dst = (zb < 8) ? (u + zb * 2048) : (outz + (zb - 8) * 2048);
        for (int i = tid; i < 2048; i += 256) dst[i] = 0.f;
    }
}

// ---- QK projection: 4-buf gload_lds, 2 K-tiles per barrier (r22 best) ----
__global__ __launch_bounds__(256) void k_qkproj(const float* __restrict__ x,
                                                const u16* __restrict__ wt,
                                                const float* __restrict__ bq,
                                                const float* __restrict__ bk,
                                                u16* __restrict__ qk) {
    __shared__ __align__(16) u16 Bs[4][128 * 64];
    int tid = threadIdx.x, l6 = tid & 63, w = tid >> 6;
    int lr = l6 & 15, lk = l6 >> 4;
    int row = blockIdx.x * 64 + w * 16;
    const float* xr = x + (size_t)(row + lr) * HH + lk * 8;
    int r0 = tid >> 3, j = tid & 7;
    const u16* bsrc = wt + (size_t)r0 * HH + (j ^ (r0 & 7)) * 8;
    float4 xa0[4], xa1[4];
    #define GLOADB(kt, BI) { const u16* s_ = bsrc + (kt) * 64; u16* l_ = Bs[BI] + tid * 8;  \
        gload16(s_,            l_);        gload16(s_ + 32 * HH, l_ + 2048);                \
        gload16(s_ + 64 * HH,  l_ + 4096); gload16(s_ + 96 * HH, l_ + 6144); }
    #define LOADA(kt, A_) { const float* p_ = xr + (kt) * 64;                               \
        A_[0] = *(const float4*)p_;        A_[1] = *(const float4*)(p_ + 4);                \
        A_[2] = *(const float4*)(p_ + 32); A_[3] = *(const float4*)(p_ + 36); }
    #define COMP(BI, A_) { const u16* Bp = Bs[BI];                                          \
        bf16x8 a0 = cvt8(A_[0], A_[1]);                                                     \
        bf16x8 a1 = cvt8(A_[2], A_[3]);                                                     \
        _Pragma("unroll")                                                                   \
        for (int jj = 0; jj < 8; ++jj) {                                                    \
            bf16x8 b0 = ldfrag(Bp, jj * 16, 0, l6);                                         \
            bf16x8 b1 = ldfrag(Bp, jj * 16, 1, l6);                                         \
            acc[jj] = MFMA16(a0, b0, acc[jj], 0, 0, 0);                                     \
            acc[jj] = MFMA16(a1, b1, acc[jj], 0, 0, 0);                                     \
        } }

    f32x4 acc[8];
    #pragma unroll
    for (int jj = 0; jj < 8; ++jj) acc[jj] = (f32x4){0.f, 0.f, 0.f, 0.f};

    GLOADB(0, 0); GLOADB(1, 1); LOADA(0, xa0); LOADA(1, xa1);
    __syncthreads();                               // tiles 0,1 resident
    for (int p = 0; p < 8; ++p) {
        int k0 = 2 * p;
        if (p < 7) { GLOADB(k0 + 2, (k0 + 2) & 3); GLOADB(k0 + 3, (k0 + 3) & 3); }
        __builtin_amdgcn_s_setprio(1);
        COMP(k0 & 3, xa0);
        __builtin_amdgcn_s_setprio(0);
        if (p < 7) LOADA(k0 + 2, xa0);
        __builtin_amdgcn_s_setprio(1);
        COMP((k0 + 1) & 3, xa1);
        __builtin_amdgcn_s_setprio(0);
        if (p < 7) {
            LOADA(k0 + 3, xa1);
            __syncthreads();                       // drains gloads; tiles k0+2,k0+3 ready
        }
    }
    #pragma unroll
    for (int jj = 0; jj < 8; ++jj) {
        int n = jj * 16 + lr;
        float bias = (n < 64) ? bq[n] : bk[n - 64];
        int mrow = row + lk * 4;
        #pragma unroll
        for (int r4 = 0; r4 < 4; ++r4)
            qk[(size_t)(mrow + r4) * 128 + n] = f2b(acc[jj][r4] + bias);
    }
    #undef GLOADB
    #undef LOADA
    #undef COMP
}

// ---- score: 32x32 MFMA, wave owns 32 cols; K dbuf gload_lds; XCD remap; setprio ----
// acc layout (m74/m101): col = lane&31, row = (reg&3) + 8*(reg>>2) + 4*(lane>>5)
__global__ __launch_bounds__(256) void k_score(const u16* __restrict__ qk,
                                               const int* __restrict__ mask,
                                               float* __restrict__ cpart) {
    __shared__ __align__(16) u16 Ks0[128 * 64];
    __shared__ __align__(16) u16 Ks1[128 * 64];
    __shared__ float pml[SS];          // additive key mask: 0 or -1e30
    __shared__ float redbuf[4][64];
    __shared__ float lshs[64];
    // XCD-locality remap (T1): each XCD owns 2 whole batches -> K-half L2-resident
    int l = blockIdx.x;
    int b = (l & 7) * 2 + ((l >> 3) >> 5);
    int sb = (l >> 3) & 31;
    int tid = threadIdx.x, l6 = tid & 63, w = tid >> 6;
    int cl = l6 & 31, hi = l6 >> 5;
    for (int i = tid; i < SS; i += 256) pml[i] = mask[b * SS + i] ? 0.f : -1e30f;
    const u16* qkb = qk + (size_t)b * SS * 128;
    int q0 = sb * 64;
    bf16x8 qA[2][4];
    #pragma unroll
    for (int rs = 0; rs < 2; ++rs)
        #pragma unroll
        for (int ks = 0; ks < 4; ++ks)
            qA[rs][ks] = *(const bf16x8*)&qkb[(size_t)(q0 + rs * 32 + cl) * 128 + ks * 16 + hi * 8];
    int r0 = tid >> 3, j = tid & 7;
    const u16* ksrc = qkb + 64 + (size_t)r0 * 128 + (j ^ (r0 & 7)) * 8;
    #define GLOADK(tt, B_) { const u16* s_ = ksrc + (size_t)(tt) * (128 * 128); u16* l_ = B_ + tid * 8; \
        gload16(s_,             l_);        gload16(s_ + 32 * 128, l_ + 2048);                          \
        gload16(s_ + 64 * 128,  l_ + 4096); gload16(s_ + 96 * 128, l_ + 6144); }

    const float SCL = 0.18033688f;     // log2(e)/8
    GLOADK(0, Ks0);
    __syncthreads();                   // pml + tile 0 resident
    // ---- pass 1: row sums of masked exp ----
    float rsum[2][16];
    #pragma unroll
    for (int rs = 0; rs < 2; ++rs)
        #pragma unroll
        for (int r = 0; r < 16; ++r) rsum[rs][r] = 0.f;
    for (int tt = 0; tt < 16; ++tt) {
        const u16* Ks = (tt & 1) ? Ks1 : Ks0;
        if (tt < 15) {
            if (tt & 1) { GLOADK(tt + 1, Ks0); } else { GLOADK(tt + 1, Ks1); }
        }
        bf16x8 kB[4];
        #pragma unroll
        for (int ks = 0; ks < 4; ++ks)
            kB[ks] = *(const bf16x8*)&Ks[swze(w * 32 + cl, ks * 16 + hi * 8)];
        float pmv = pml[tt * 128 + w * 32 + cl];
        __builtin_amdgcn_s_setprio(1);
        #pragma unroll
        for (int rs = 0; rs < 2; ++rs) {
            f32x16 acc = {};
            #pragma unroll
            for (int ks = 0; ks < 4; ++ks) acc = MFMA32(qA[rs][ks], kB[ks], acc, 0, 0, 0);
            #pragma unroll
            for (int r = 0; r < 16; ++r)
                rsum[rs][r] += exp2f(fmaf(acc[r], SCL, pmv));
        }
        __builtin_amdgcn_s_setprio(0);
        if (tt < 15) __syncthreads();
    }
    // reduce over this wave's 32 cols (low 5 lane bits)
    #pragma unroll
    for (int off = 1; off < 32; off <<= 1)
        #pragma unroll
        for (int rs = 0; rs < 2; ++rs)
            #pragma unroll
            for (int r = 0; r < 16; ++r)
                rsum[rs][r] += __shfl_xor(rsum[rs][r], off);
    if (cl == 0) {
        #pragma unroll
        for (int rs = 0; rs < 2; ++rs)
            #pragma unroll
            for (int r = 0; r < 16; ++r)
                redbuf[w][rs * 32 + (r & 3) + 8 * (r >> 2) + 4 * hi] = rsum[rs][r];
    }
    GLOADK(0, Ks0);                    // prefetch pass-2 tile 0
    __syncthreads();
    if (tid < 64) {
        float lv = redbuf[0][tid] + redbuf[1][tid] + redbuf[2][tid] + redbuf[3][tid];
        lshs[tid] = (lv > 0.f) ? -log2f(lv) : -1e30f;
    }
    __syncthreads();
    float lsh[2][16];
    unsigned qmb = 0;
    #pragma unroll
    for (int rs = 0; rs < 2; ++rs)
        #pragma unroll
        for (int r = 0; r < 16; ++r) {
            int rowi = rs * 32 + (r & 3) + 8 * (r >> 2) + 4 * hi;
            lsh[rs][r] = lshs[rowi];
            qmb |= (pml[q0 + rowi] == 0.f ? 1u : 0u) << (rs * 16 + r);
        }
    // ---- pass 2: column sums (wave-local: in-reg over rows + shfl(32)) ----
    for (int tt = 0; tt < 16; ++tt) {
        const u16* Ks = (tt & 1) ? Ks1 : Ks0;
        if (tt < 15) {
            if (tt & 1) { GLOADK(tt + 1, Ks0); } else { GLOADK(tt + 1, Ks1); }
        }
        bf16x8 kB[4];
        #pragma unroll
        for (int ks = 0; ks < 4; ++ks)
            kB[ks] = *(const bf16x8*)&Ks[swze(w * 32 + cl, ks * 16 + hi * 8)];
        float pmv = pml[tt * 128 + w * 32 + cl];
        float sa = 0.f, sm = 0.f;
        __builtin_amdgcn_s_setprio(1);
        #pragma unroll
        for (int rs = 0; rs < 2; ++rs) {
            f32x16 acc = {};
            #pragma unroll
            for (int ks = 0; ks < 4; ++ks) acc = MFMA32(qA[rs][ks], kB[ks], acc, 0, 0, 0);
            #pragma unroll
            for (int r = 0; r < 16; ++r) {
                float e = exp2f(fmaf(acc[r], SCL, lsh[rs][r]) + pmv);
                sa += e;
                sm += ((qmb >> (rs * 16 + r)) & 1u) ? e : 0.f;
            }
        }
        __builtin_amdgcn_s_setprio(0);
        sa += __shfl_xor(sa, 32);
        sm += __shfl_xor(sm, 32);
        if (hi == 0) {
            size_t base = (((size_t)b * 32 + sb) * 2) * SS + tt * 128 + w * 32 + cl;
            cpart[base] = sa;
            cpart[base + SS] = sm;
        }
        if (tt < 15) __syncthreads();
    }
    #undef GLOADK
}

// ---- k_u (+fused finalize): w + attn_mean from cpart, then atomic u accumulate ----
__global__ __launch_bounds__(256) void k_u(const float* __restrict__ x,
                                           const float* __restrict__ cpart,
                                           const int* __restrict__ mask,
                                           const float* __restrict__ nbv,
                                           float* __restrict__ u,
                                           float* __restrict__ out_mean) {
    __shared__ float wl[64];
    __shared__ float red2[2][4][64];
    int b = blockIdx.x, ch = blockIdx.y;
    int tid = threadIdx.x, tl = tid & 63, qd = tid >> 6;
    int t = ch * 64 + tl;
    float sa = 0.f, sm = 0.f;
    #pragma unroll
    for (int k = 0; k < 8; ++k) {
        const float* p = &cpart[(((size_t)b * 32 + (qd * 8 + k)) * 2) * SS + t];
        sa += p[0];
        sm += p[SS];
    }
    red2[0][qd][tl] = sa;
    red2[1][qd][tl] = sm;
    __syncthreads();
    if (tid < 64) {
        float sat = red2[0][0][tl] + red2[0][1][tl] + red2[0][2][tl] + red2[0][3][tl];
        float smt = red2[1][0][tl] + red2[1][1][tl] + red2[1][2][tl] + red2[1][3][tl];
        float pm = mask[b * SS + t] ? 1.f : 0.f;
        out_mean[b * SS + t] = sat * pm * (1.f / SS);
        wl[tl] = smt * pm / nbv[b];
    }
    __syncthreads();
    const float* xb = &x[((size_t)b * SS + ch * 64) * HH + tid * 4];
    float4 acc = {0.f, 0.f, 0.f, 0.f};
    #pragma unroll 16
    for (int tt = 0; tt < 64; ++tt) {
        float4 xv = *(const float4*)&xb[(size_t)tt * HH];
        float wv = wl[tt];
        acc.x += wv * xv.x; acc.y += wv * xv.y;
        acc.z += wv * xv.z; acc.w += wv * xv.w;
    }
    float* up = &u[(size_t)b * HH + tid * 4];
    atomicAdd(&up[0], acc.x);
    atomicAdd(&up[1], acc.y);
    atomicAdd(&up[2], acc.z);
    atomicAdd(&up[3], acc.w);
}

// ---- out0: 256 blocks (16 cb x 16 hb), 64c x 64h Wv tile, 16 acc/thread ----
__global__ __launch_bounds__(256) void k_out0a(const float* __restrict__ u,
                                               const float* __restrict__ Wv,
                                               const float* __restrict__ bv,
                                               const float* __restrict__ nbw,
                                               float* __restrict__ out) {
    __shared__ float uT[64][16];
    __shared__ float red[4][64][16];
    int cb = blockIdx.x, hb = blockIdx.y;
    int c0 = cb * 64, h0 = hb * 64;
    int tid = threadIdx.x;
    int hl = tid & 63, cq = tid >> 6;
    #pragma unroll
    for (int it = 0; it < 4; ++it) {
        int b = it * 4 + cq;
        uT[hl][b] = u[(size_t)b * HH + c0 + hl];
    }
    __syncthreads();
    int h = h0 + hl;
    float acc[16];
    #pragma unroll
    for (int b = 0; b < 16; ++b) acc[b] = 0.f;
    #pragma unroll
    for (int cc = 0; cc < 16; ++cc) {
        int c = cq * 16 + cc;
        float wv = Wv[(size_t)(c0 + c) * HH + h];
        #pragma unroll
        for (int b = 0; b < 16; ++b) acc[b] += uT[c][b] * wv;
    }
    #pragma unroll
    for (int b = 0; b < 16; ++b) red[cq][hl][b] = acc[b];
    __syncthreads();
    #pragma unroll
    for (int it = 0; it < 4; ++it) {
        int b = it * 4 + cq;
        float s = red[0][hl][b] + red[1][hl][b] + red[2][hl][b] + red[3][hl][b];
        if (cb == 0) s += bv[h] * nbw[b];
        atomicAdd(&out[(size_t)b * HH + h], s);
    }
}

extern "C" void kernel_launch(void* const* d_in, const int* in_sizes, int n_in,
                              void* d_out, int out_size, void* d_ws, size_t ws_size,
                              hipStream_t stream) {
    const float* x  = (const float*)d_in[0];
    const int* mask = (const int*)d_in[1];
    const float* Wq = (const float*)d_in[2];
    const float* bq = (const float*)d_in[3];
    const float* Wk = (const float*)d_in[4];
    const float* bk = (const float*)d_in[5];
    const float* Wv = (const float*)d_in[6];
    const float* bv = (const float*)d_in[7];
    float* out = (float*)d_out;
    float* ws  = (float*)d_ws;

    u16*   qk    = (u16*)(ws + QK_OFF);
    u16*   wt    = (u16*)(ws + WT_OFF);
    float* cpart = ws + CP_OFF;
    float* nbv   = ws + NB_OFF;
    float* nbw   = ws + NBW_OFF;
    float* u     = ws + U_OFF;

    k_prep   <<<dim3(160),        dim3(256), 0, stream>>>(Wq, Wk, mask, wt, nbv, nbw, u, out);
    k_qkproj <<<dim3(512),        dim3(256), 0, stream>>>(x, wt, bq, bk, qk);
    k_score  <<<dim3(512),        dim3(256), 0, stream>>>(qk, mask, cpart);
    k_u      <<<dim3(BN_, 32),    dim3(256), 0, stream>>>(x, cpart, mask, nbv, u, out + BN_ * HH);
    k_out0a  <<<dim3(16, 16),     dim3(256), 0, stream>>>(u, Wv, bv, nbw, out);
}

// Round 27
// 127.264 us; speedup vs baseline: 1.2507x; 1.0034x over previous
//
#include <hip/hip_runtime.h>
#include <math.h>

#define BN_ 16
#define SS  2048
#define HH  1024

typedef unsigned short u16;
typedef unsigned int   u32;
typedef __bf16 bf16x8 __attribute__((ext_vector_type(8)));
typedef float  f32x4  __attribute__((ext_vector_type(4)));
typedef float  f32x16 __attribute__((ext_vector_type(16)));
#define MFMA16 __builtin_amdgcn_mfma_f32_16x16x32_bf16
#define MFMA32 __builtin_amdgcn_mfma_f32_32x32x16_bf16

// ---------------- ws layout (float offsets) ----------------
#define QK_OFF    0
#define QK_FLOATS (BN_*SS*64)           // bf16 qk[32768][128]
#define WT_OFF    (QK_OFF + QK_FLOATS)  // bf16 wt[128][1024]
#define WT_FLOATS (64*HH)
#define CP_OFF    (WT_OFF + WT_FLOATS)  // cpart[16][32][2][2048]
#define CP_FLOATS (BN_*32*2*SS)
#define NB_OFF    (CP_OFF + CP_FLOATS)  // nbv [16]
#define NBW_OFF   (NB_OFF + 16)         // nbw [16]
#define U_OFF     (NBW_OFF + 16)        // u[16][1024] fp32 (atomic-accumulated)

__device__ __forceinline__ u16 f2b(float f) {
    unsigned u = __builtin_bit_cast(unsigned, f);
    return (u16)((u + 0x7FFFu + ((u >> 16) & 1u)) >> 16);
}

__device__ __forceinline__ bf16x8 cvt8(float4 a, float4 b) {
    bf16x8 r;
    r[0] = (__bf16)a.x; r[1] = (__bf16)a.y; r[2] = (__bf16)a.z; r[3] = (__bf16)a.w;
    r[4] = (__bf16)b.x; r[5] = (__bf16)b.y; r[6] = (__bf16)b.z; r[7] = (__bf16)b.w;
    return r;
}

// swizzled elem index in a [rows][64] bf16 LDS tile (row stride 128B)
__device__ __forceinline__ int swze(int row, int e) {
    return row * 64 + (e ^ ((row & 7) << 3));
}

// MFMA16 A/B fragment from swizzled tile
__device__ __forceinline__ bf16x8 ldfrag(const u16* t, int row16, int ks, int l6) {
    int row = row16 + (l6 & 15);
    int e = ks * 32 + ((l6 >> 4) << 3);
    return *(const bf16x8*)&t[swze(row, e)];
}

// async global->LDS, 16B per lane; LDS dest = wave-uniform base + lane*16
__device__ __forceinline__ void gload16(const u16* g, u16* l) {
    __builtin_amdgcn_global_load_lds(
        (const __attribute__((address_space(1))) u32*)g,
        (__attribute__((address_space(3))) u32*)l, 16, 0, 0);
}

// ---- prep: wt transpose (0..127) + Nb (128..143) + zero u/out0 (144..159) ----
__global__ __launch_bounds__(256) void k_prep(const float* __restrict__ Wq,
                                              const float* __restrict__ Wk,
                                              const int* __restrict__ mask,
                                              u16* __restrict__ wt,
                                              float* __restrict__ nbv,
                                              float* __restrict__ nbw,
                                              float* __restrict__ u,
                                              float* __restrict__ outz) {
    int bid = blockIdx.x, tid = threadIdx.x;
    if (bid < 128) {
        const float* src = (bid < 64) ? &Wq[bid] : &Wk[bid - 64];
        for (int k = tid; k < HH; k += 256)
            wt[(size_t)bid * HH + k] = f2b(src[(size_t)k * 64]);
    } else if (bid < 144) {
        int b = bid - 128;
        int s = 0;
        for (int i = tid; i < SS; i += 256) s += mask[b * SS + i];
        float fs = (float)s;
        for (int off = 1; off < 64; off <<= 1) fs += __shfl_xor(fs, off);
        __shared__ float red[4];
        if ((tid & 63) == 0) red[tid >> 6] = fs;
        __syncthreads();
        if (tid == 0) {
            float t = red[0] + red[1] + red[2] + red[3];
            nbv[b] = t + 1e-8f;
            nbw[b] = t / (t + 1e-8f);
        }
    } else {
        int zb = bid - 144;                           // 0..15, 2048 floats each
        float* dst = (zb < 8) ? (u + zb * 2048) : (outz + (zb - 8) * 2048);
        for (int i = tid; i < 2048; i += 256) dst[i] = 0.f;
    }
}

// ---- QK projection: 4-buf gload_lds, 2 K-tiles per barrier (r22 best) ----
__global__ __launch_bounds__(256) void k_qkproj(const float* __restrict__ x,
                                                const u16* __restrict__ wt,
                                                const float* __restrict__ bq,
                                                const float* __restrict__ bk,
                                                u16* __restrict__ qk) {
    __shared__ __align__(16) u16 Bs[4][128 * 64];
    int tid = threadIdx.x, l6 = tid & 63, w = tid >> 6;
    int lr = l6 & 15, lk = l6 >> 4;
    int row = blockIdx.x * 64 + w * 16;
    const float* xr = x + (size_t)(row + lr) * HH + lk * 8;
    int r0 = tid >> 3, j = tid & 7;
    const u16* bsrc = wt + (size_t)r0 * HH + (j ^ (r0 & 7)) * 8;
    float4 xa0[4], xa1[4];
    #define GLOADB(kt, BI) { const u16* s_ = bsrc + (kt) * 64; u16* l_ = Bs[BI] + tid * 8;  \
        gload16(s_,            l_);        gload16(s_ + 32 * HH, l_ + 2048);                \
        gload16(s_ + 64 * HH,  l_ + 4096); gload16(s_ + 96 * HH, l_ + 6144); }
    #define LOADA(kt, A_) { const float* p_ = xr + (kt) * 64;                               \
        A_[0] = *(const float4*)p_;        A_[1] = *(const float4*)(p_ + 4);                \
        A_[2] = *(const float4*)(p_ + 32); A_[3] = *(const float4*)(p_ + 36); }
    #define COMP(BI, A_) { const u16* Bp = Bs[BI];                                          \
        bf16x8 a0 = cvt8(A_[0], A_[1]);                                                     \
        bf16x8 a1 = cvt8(A_[2], A_[3]);                                                     \
        _Pragma("unroll")                                                                   \
        for (int jj = 0; jj < 8; ++jj) {                                                    \
            bf16x8 b0 = ldfrag(Bp, jj * 16, 0, l6);                                         \
            bf16x8 b1 = ldfrag(Bp, jj * 16, 1, l6);                                         \
            acc[jj] = MFMA16(a0, b0, acc[jj], 0, 0, 0);                                     \
            acc[jj] = MFMA16(a1, b1, acc[jj], 0, 0, 0);                                     \
        } }

    f32x4 acc[8];
    #pragma unroll
    for (int jj = 0; jj < 8; ++jj) acc[jj] = (f32x4){0.f, 0.f, 0.f, 0.f};

    GLOADB(0, 0); GLOADB(1, 1); LOADA(0, xa0); LOADA(1, xa1);
    __syncthreads();                               // tiles 0,1 resident
    for (int p = 0; p < 8; ++p) {
        int k0 = 2 * p;
        if (p < 7) { GLOADB(k0 + 2, (k0 + 2) & 3); GLOADB(k0 + 3, (k0 + 3) & 3); }
        __builtin_amdgcn_s_setprio(1);
        COMP(k0 & 3, xa0);
        __builtin_amdgcn_s_setprio(0);
        if (p < 7) LOADA(k0 + 2, xa0);
        __builtin_amdgcn_s_setprio(1);
        COMP((k0 + 1) & 3, xa1);
        __builtin_amdgcn_s_setprio(0);
        if (p < 7) {
            LOADA(k0 + 3, xa1);
            __syncthreads();                       // drains gloads; tiles k0+2,k0+3 ready
        }
    }
    #pragma unroll
    for (int jj = 0; jj < 8; ++jj) {
        int n = jj * 16 + lr;
        float bias = (n < 64) ? bq[n] : bk[n - 64];
        int mrow = row + lk * 4;
        #pragma unroll
        for (int r4 = 0; r4 < 4; ++r4)
            qk[(size_t)(mrow + r4) * 128 + n] = f2b(acc[jj][r4] + bias);
    }
    #undef GLOADB
    #undef LOADA
    #undef COMP
}

// ---- score: 32x32 MFMA, wave owns 32 cols; K dbuf gload_lds; XCD remap; setprio ----
// acc layout (m74/m101): col = lane&31, row = (reg&3) + 8*(reg>>2) + 4*(lane>>5)
__global__ __launch_bounds__(256) void k_score(const u16* __restrict__ qk,
                                               const int* __restrict__ mask,
                                               float* __restrict__ cpart) {
    __shared__ __align__(16) u16 Ks0[128 * 64];
    __shared__ __align__(16) u16 Ks1[128 * 64];
    __shared__ float pml[SS];          // additive key mask: 0 or -1e30
    __shared__ float redbuf[4][64];
    __shared__ float lshs[64];
    // XCD-locality remap (T1): each XCD owns 2 whole batches -> K-half L2-resident
    int l = blockIdx.x;
    int b = (l & 7) * 2 + ((l >> 3) >> 5);
    int sb = (l >> 3) & 31;
    int tid = threadIdx.x, l6 = tid & 63, w = tid >> 6;
    int cl = l6 & 31, hi = l6 >> 5;
    for (int i = tid; i < SS; i += 256) pml[i] = mask[b * SS + i] ? 0.f : -1e30f;
    const u16* qkb = qk + (size_t)b * SS * 128;
    int q0 = sb * 64;
    bf16x8 qA[2][4];
    #pragma unroll
    for (int rs = 0; rs < 2; ++rs)
        #pragma unroll
        for (int ks = 0; ks < 4; ++ks)
            qA[rs][ks] = *(const bf16x8*)&qkb[(size_t)(q0 + rs * 32 + cl) * 128 + ks * 16 + hi * 8];
    int r0 = tid >> 3, j = tid & 7;
    const u16* ksrc = qkb + 64 + (size_t)r0 * 128 + (j ^ (r0 & 7)) * 8;
    #define GLOADK(tt, B_) { const u16* s_ = ksrc + (size_t)(tt) * (128 * 128); u16* l_ = B_ + tid * 8; \
        gload16(s_,             l_);        gload16(s_ + 32 * 128, l_ + 2048);                          \
        gload16(s_ + 64 * 128,  l_ + 4096); gload16(s_ + 96 * 128, l_ + 6144); }

    const float SCL = 0.18033688f;     // log2(e)/8
    GLOADK(0, Ks0);
    __syncthreads();                   // pml + tile 0 resident
    // ---- pass 1: row sums of masked exp ----
    float rsum[2][16];
    #pragma unroll
    for (int rs = 0; rs < 2; ++rs)
        #pragma unroll
        for (int r = 0; r < 16; ++r) rsum[rs][r] = 0.f;
    for (int tt = 0; tt < 16; ++tt) {
        const u16* Ks = (tt & 1) ? Ks1 : Ks0;
        if (tt < 15) {
            if (tt & 1) { GLOADK(tt + 1, Ks0); } else { GLOADK(tt + 1, Ks1); }
        }
        bf16x8 kB[4];
        #pragma unroll
        for (int ks = 0; ks < 4; ++ks)
            kB[ks] = *(const bf16x8*)&Ks[swze(w * 32 + cl, ks * 16 + hi * 8)];
        float pmv = pml[tt * 128 + w * 32 + cl];
        __builtin_amdgcn_s_setprio(1);
        #pragma unroll
        for (int rs = 0; rs < 2; ++rs) {
            f32x16 acc = {};
            #pragma unroll
            for (int ks = 0; ks < 4; ++ks) acc = MFMA32(qA[rs][ks], kB[ks], acc, 0, 0, 0);
            #pragma unroll
            for (int r = 0; r < 16; ++r)
                rsum[rs][r] += exp2f(fmaf(acc[r], SCL, pmv));
        }
        __builtin_amdgcn_s_setprio(0);
        if (tt < 15) __syncthreads();
    }
    // reduce over this wave's 32 cols (low 5 lane bits)
    #pragma unroll
    for (int off = 1; off < 32; off <<= 1)
        #pragma unroll
        for (int rs = 0; rs < 2; ++rs)
            #pragma unroll
            for (int r = 0; r < 16; ++r)
                rsum[rs][r] += __shfl_xor(rsum[rs][r], off);
    if (cl == 0) {
        #pragma unroll
        for (int rs = 0; rs < 2; ++rs)
            #pragma unroll
            for (int r = 0; r < 16; ++r)
                redbuf[w][rs * 32 + (r & 3) + 8 * (r >> 2) + 4 * hi] = rsum[rs][r];
    }
    GLOADK(0, Ks0);                    // prefetch pass-2 tile 0
    __syncthreads();
    if (tid < 64) {
        float lv = redbuf[0][tid] + redbuf[1][tid] + redbuf[2][tid] + redbuf[3][tid];
        lshs[tid] = (lv > 0.f) ? -log2f(lv) : -1e30f;
    }
    __syncthreads();
    float lsh[2][16];
    unsigned qmb = 0;
    #pragma unroll
    for (int rs = 0; rs < 2; ++rs)
        #pragma unroll
        for (int r = 0; r < 16; ++r) {
            int rowi = rs * 32 + (r & 3) + 8 * (r >> 2) + 4 * hi;
            lsh[rs][r] = lshs[rowi];
            qmb |= (pml[q0 + rowi] == 0.f ? 1u : 0u) << (rs * 16 + r);
        }
    // ---- pass 2: column sums (wave-local: in-reg over rows + shfl(32)) ----
    for (int tt = 0; tt < 16; ++tt) {
        const u16* Ks = (tt & 1) ? Ks1 : Ks0;
        if (tt < 15) {
            if (tt & 1) { GLOADK(tt + 1, Ks0); } else { GLOADK(tt + 1, Ks1); }
        }
        bf16x8 kB[4];
        #pragma unroll
        for (int ks = 0; ks < 4; ++ks)
            kB[ks] = *(const bf16x8*)&Ks[swze(w * 32 + cl, ks * 16 + hi * 8)];
        float pmv = pml[tt * 128 + w * 32 + cl];
        float sa = 0.f, sm = 0.f;
        __builtin_amdgcn_s_setprio(1);
        #pragma unroll
        for (int rs = 0; rs < 2; ++rs) {
            f32x16 acc = {};
            #pragma unroll
            for (int ks = 0; ks < 4; ++ks) acc = MFMA32(qA[rs][ks], kB[ks], acc, 0, 0, 0);
            #pragma unroll
            for (int r = 0; r < 16; ++r) {
                float e = exp2f(fmaf(acc[r], SCL, lsh[rs][r]) + pmv);
                sa += e;
                sm += ((qmb >> (rs * 16 + r)) & 1u) ? e : 0.f;
            }
        }
        __builtin_amdgcn_s_setprio(0);
        sa += __shfl_xor(sa, 32);
        sm += __shfl_xor(sm, 32);
        if (hi == 0) {
            size_t base = (((size_t)b * 32 + sb) * 2) * SS + tt * 128 + w * 32 + cl;
            cpart[base] = sa;
            cpart[base + SS] = sm;
        }
        if (tt < 15) __syncthreads();
    }
    #undef GLOADK
}

// ---- k_u (+fused finalize): w + attn_mean from cpart, then atomic u accumulate ----
__global__ __launch_bounds__(256) void k_u(const float* __restrict__ x,
                                           const float* __restrict__ cpart,
                                           const int* __restrict__ mask,
                                           const float* __restrict__ nbv,
                                           float* __restrict__ u,
                                           float* __restrict__ out_mean) {
    __shared__ float wl[64];
    __shared__ float red2[2][4][64];
    int b = blockIdx.x, ch = blockIdx.y;
    int tid = threadIdx.x, tl = tid & 63, qd = tid >> 6;
    int t = ch * 64 + tl;
    float sa = 0.f, sm = 0.f;
    #pragma unroll
    for (int k = 0; k < 8; ++k) {
        const float* p = &cpart[(((size_t)b * 32 + (qd * 8 + k)) * 2) * SS + t];
        sa += p[0];
        sm += p[SS];
    }
    red2[0][qd][tl] = sa;
    red2[1][qd][tl] = sm;
    __syncthreads();
    if (tid < 64) {
        float sat = red2[0][0][tl] + red2[0][1][tl] + red2[0][2][tl] + red2[0][3][tl];
        float smt = red2[1][0][tl] + red2[1][1][tl] + red2[1][2][tl] + red2[1][3][tl];
        float pm = mask[b * SS + t] ? 1.f : 0.f;
        out_mean[b * SS + t] = sat * pm * (1.f / SS);
        wl[tl] = smt * pm / nbv[b];
    }
    __syncthreads();
    const float* xb = &x[((size_t)b * SS + ch * 64) * HH + tid * 4];
    float4 acc = {0.f, 0.f, 0.f, 0.f};
    #pragma unroll 16
    for (int tt = 0; tt < 64; ++tt) {
        float4 xv = *(const float4*)&xb[(size_t)tt * HH];
        float wv = wl[tt];
        acc.x += wv * xv.x; acc.y += wv * xv.y;
        acc.z += wv * xv.z; acc.w += wv * xv.w;
    }
    float* up = &u[(size_t)b * HH + tid * 4];
    atomicAdd(&up[0], acc.x);
    atomicAdd(&up[1], acc.y);
    atomicAdd(&up[2], acc.z);
    atomicAdd(&up[3], acc.w);
}

// ---- out0: 256 blocks (16 cb x 16 hb), 64c x 64h Wv tile, 16 acc/thread ----
__global__ __launch_bounds__(256) void k_out0a(const float* __restrict__ u,
                                               const float* __restrict__ Wv,
                                               const float* __restrict__ bv,
                                               const float* __restrict__ nbw,
                                               float* __restrict__ out) {
    __shared__ float uT[64][16];
    __shared__ float red[4][64][16];
    int cb = blockIdx.x, hb = blockIdx.y;
    int c0 = cb * 64, h0 = hb * 64;
    int tid = threadIdx.x;
    int hl = tid & 63, cq = tid >> 6;
    #pragma unroll
    for (int it = 0; it < 4; ++it) {
        int b = it * 4 + cq;
        uT[hl][b] = u[(size_t)b * HH + c0 + hl];
    }
    __syncthreads();
    int h = h0 + hl;
    float acc[16];
    #pragma unroll
    for (int b = 0; b < 16; ++b) acc[b] = 0.f;
    #pragma unroll
    for (int cc = 0; cc < 16; ++cc) {
        int c = cq * 16 + cc;
        float wv = Wv[(size_t)(c0 + c) * HH + h];
        #pragma unroll
        for (int b = 0; b < 16; ++b) acc[b] += uT[c][b] * wv;
    }
    #pragma unroll
    for (int b = 0; b < 16; ++b) red[cq][hl][b] = acc[b];
    __syncthreads();
    #pragma unroll
    for (int it = 0; it < 4; ++it) {
        int b = it * 4 + cq;
        float s = red[0][hl][b] + red[1][hl][b] + red[2][hl][b] + red[3][hl][b];
        if (cb == 0) s += bv[h] * nbw[b];
        atomicAdd(&out[(size_t)b * HH + h], s);
    }
}

extern "C" void kernel_launch(void* const* d_in, const int* in_sizes, int n_in,
                              void* d_out, int out_size, void* d_ws, size_t ws_size,
                              hipStream_t stream) {
    const float* x  = (const float*)d_in[0];
    const int* mask = (const int*)d_in[1];
    const float* Wq = (const float*)d_in[2];
    const float* bq = (const float*)d_in[3];
    const float* Wk = (const float*)d_in[4];
    const float* bk = (const float*)d_in[5];
    const float* Wv = (const float*)d_in[6];
    const float* bv = (const float*)d_in[7];
    float* out = (float*)d_out;
    float* ws  = (float*)d_ws;

    u16*   qk    = (u16*)(ws + QK_OFF);
    u16*   wt    = (u16*)(ws + WT_OFF);
    float* cpart = ws + CP_OFF;
    float* nbv   = ws + NB_OFF;
    float* nbw   = ws + NBW_OFF;
    float* u     = ws + U_OFF;

    k_prep   <<<dim3(160),        dim3(256), 0, stream>>>(Wq, Wk, mask, wt, nbv, nbw, u, out);
    k_qkproj <<<dim3(512),        dim3(256), 0, stream>>>(x, wt, bq, bk, qk);
    k_score  <<<dim3(512),        dim3(256), 0, stream>>>(qk, mask, cpart);
    k_u      <<<dim3(BN_, 32),    dim3(256), 0, stream>>>(x, cpart, mask, nbv, u, out + BN_ * HH);
    k_out0a  <<<dim3(16, 16),     dim3(256), 0, stream>>>(u, Wv, bv, nbw, out);
}